// Round 5
// baseline (90.688 us; speedup 1.0000x reference)
//
#include <hip/hip_runtime.h>

typedef __attribute__((ext_vector_type(8))) __bf16 bf16x8;
typedef __attribute__((ext_vector_type(4))) __bf16 bf16x4;
typedef __attribute__((ext_vector_type(4))) float f32x4;

namespace {
constexpr int N_ = 64, C_ = 512, P_ = 900, K_ = 64;
constexpr int PP = 960;                               // padded P for at
constexpr size_t TOT_X = (size_t)N_ * C_ * P_;        // 117,964,800 floats
constexpr size_t AT_BYTES  = (size_t)N_ * K_ * PP * 2;        // bf16 a' [n][k][960]
constexpr size_t ASUM_OFF  = AT_BYTES;                        // f32 [n][k]
constexpr size_t WB_OFF    = ASUM_OFF + (size_t)N_ * K_ * 4;  // bf16 w [k][c]
}

// --- w f32 [K][C] -> bf16 [K][C]; also zero asum (replaces a memset dispatch)
__global__ __launch_bounds__(256) void k_prep_w(const float* __restrict__ w,
                                                __bf16* __restrict__ wb,
                                                float* __restrict__ asum) {
  const int t = blockIdx.x * 256 + threadIdx.x;
  const int i = t * 4;
  if (i < K_ * C_) {
    float4 v = *reinterpret_cast<const float4*>(w + i);
    wb[i]   = (__bf16)v.x; wb[i+1] = (__bf16)v.y;
    wb[i+2] = (__bf16)v.z; wb[i+3] = (__bf16)v.w;
  }
  if (t < N_ * K_) asum[t] = 0.f;
}

// --- phase 1: logits^T[k][p] via MFMA, fused ssq + maxless softmax.
//     Block: (p-tile 64, n). Wave w owns k rows [16w,16w+16).
//     Staging: thread (w,l) loads 8 dwords = c-octet w*8..w*8+8 (stepped) for p=l;
//     writes ONE b128 into padded-row LDS. Double-buffered, 1 barrier/step.
__global__ __launch_bounds__(256) void k_phase1(const float* __restrict__ x,
                                                const __bf16* __restrict__ wb,
                                                __bf16* __restrict__ at,
                                                float* __restrict__ asum) {
  __shared__ __bf16 Xl[2][64][40];   // [buf][p][c32+pad]
  __shared__ float SsqP[64][5];
  __shared__ float Sw[64][5];
  const int n   = blockIdx.y;
  const int p0  = blockIdx.x * 64;
  const int tid = threadIdx.x;
  const int w   = tid >> 6, l = tid & 63;
  const int l15 = l & 15,  lh = l >> 4;

  // preload A fragments (w rows) for all 16 K-steps: 64 VGPR
  bf16x8 afr[16];
  #pragma unroll
  for (int s = 0; s < 16; ++s)
    afr[s] = *reinterpret_cast<const bf16x8*>(
        wb + (size_t)(16 * w + l15) * C_ + s * 32 + lh * 8);

  float nx[8];
  float sq = 0.f;
  const size_t xbase = (size_t)n * C_ * P_ + p0 + l;   // p = p0 + l

  f32x4 acc[4] = {};                 // frag t: p=p0+16t+l15, k=16w+lh*4+r

  // prologue: stage step 0
  #pragma unroll
  for (int j = 0; j < 8; ++j) {
    size_t off = xbase + (size_t)(w * 8 + j) * P_;
    if (off > TOT_X - 1) off = TOT_X - 1;
    nx[j] = x[off];
  }
  {
    bf16x8 pk;
    #pragma unroll
    for (int j = 0; j < 8; ++j) { sq = fmaf(nx[j], nx[j], sq); pk[j] = (__bf16)nx[j]; }
    *reinterpret_cast<bf16x8*>(&Xl[0][l][w * 8]) = pk;
  }
  __syncthreads();

  #pragma unroll
  for (int s = 0; s < 16; ++s) {
    if (s < 15) {                      // issue next step's loads early
      #pragma unroll
      for (int j = 0; j < 8; ++j) {
        size_t off = xbase + (size_t)((s + 1) * 32 + w * 8 + j) * P_;
        if (off > TOT_X - 1) off = TOT_X - 1;
        nx[j] = x[off];
      }
    }
    #pragma unroll
    for (int t = 0; t < 4; ++t) {
      bf16x8 b = *reinterpret_cast<const bf16x8*>(&Xl[s & 1][16 * t + l15][lh * 8]);
      acc[t] = __builtin_amdgcn_mfma_f32_16x16x32_bf16(afr[s], b, acc[t], 0, 0, 0);
    }
    if (s < 15) {                      // write alternate buffer
      bf16x8 pk;
      #pragma unroll
      for (int j = 0; j < 8; ++j) { sq = fmaf(nx[j], nx[j], sq); pk[j] = (__bf16)nx[j]; }
      *reinterpret_cast<bf16x8*>(&Xl[(s + 1) & 1][l][w * 8]) = pk;
    }
    __syncthreads();
  }

  SsqP[l][w] = sq;                     // partial ssq for p=p0+l over this wave's c's
  __syncthreads();

  float invn[4], invs_[4];
  bool valid[4];
  #pragma unroll
  for (int t = 0; t < 4; ++t) {
    const int pl = 16 * t + l15;
    const float ss = SsqP[pl][0] + SsqP[pl][1] + SsqP[pl][2] + SsqP[pl][3];
    invn[t] = 1.f / fmaxf(sqrtf(ss), 1e-12f);
    valid[t] = (p0 + pl) < P_;
    float ps = 0.f;
    #pragma unroll
    for (int r = 0; r < 4; ++r) {
      acc[t][r] = __expf(acc[t][r] * invn[t]);   // maxless: |logit| <= ~0.5
      ps += acc[t][r];
    }
    ps += __shfl_xor(ps, 16, 64);
    ps += __shfl_xor(ps, 32, 64);
    if (lh == 0) Sw[pl][w] = ps;
  }
  __syncthreads();
  #pragma unroll
  for (int t = 0; t < 4; ++t) {
    const int pl = 16 * t + l15;
    invs_[t] = 1.f / (Sw[pl][0] + Sw[pl][1] + Sw[pl][2] + Sw[pl][3]);
  }

  // write a' (bf16) and asum atomics
  #pragma unroll
  for (int t = 0; t < 4; ++t) {
    const int p = p0 + 16 * t + l15;
    #pragma unroll
    for (int r = 0; r < 4; ++r) {
      const int k = 16 * w + lh * 4 + r;
      const float ar = acc[t][r] * invs_[t];
      at[((size_t)n * K_ + k) * PP + p] = valid[t] ? (__bf16)(ar * invn[t]) : (__bf16)0.f;
    }
  }
  #pragma unroll
  for (int r = 0; r < 4; ++r) {
    float v = 0.f;
    #pragma unroll
    for (int t = 0; t < 4; ++t)
      v += valid[t] ? acc[t][r] * invs_[t] : 0.f;
    v += __shfl_xor(v, 1, 64); v += __shfl_xor(v, 2, 64);
    v += __shfl_xor(v, 4, 64); v += __shfl_xor(v, 8, 64);
    if (l15 == 0)
      unsafeAtomicAdd(asum + n * K_ + 16 * w + lh * 4 + r, v);
  }
}

// --- phase 2: vlad[k][c] = sum_p a'[k][p] * x_bf16[c][p] - asum[k]*cent[k][c]
//     Block: (c-tile 64, n). Double-buffered staging, 1 barrier/step.
__global__ __launch_bounds__(256) void k_phase2(const float* __restrict__ x,
                                                const __bf16* __restrict__ at,
                                                const float* __restrict__ asum,
                                                const float* __restrict__ cent,
                                                float* __restrict__ out) {
  __shared__ __bf16 Al[2][64][40];   // [buf][k][p32+pad]
  __shared__ __bf16 Xl[2][64][40];   // [buf][c][p32+pad]
  const int n   = blockIdx.y;
  const int c0  = blockIdx.x * 64;
  const int tid = threadIdx.x;
  const int w   = tid >> 6, l = tid & 63;
  const int l15 = l & 15,  lh = l >> 4;

  const int ak  = tid >> 2, ach = tid & 3;      // A staging: k, p-octet
  const int xc  = tid >> 3, xch = tid & 7;      // X staging (×2): c, p-quad
  const size_t abase = ((size_t)n * K_ + ak) * PP + ach * 8;
  const size_t xbase0 = ((size_t)n * C_ + c0 + xc) * P_ + xch * 4;
  const size_t xbase1 = ((size_t)n * C_ + c0 + xc + 32) * P_ + xch * 4;

  f32x4 acc[4] = {};                 // frag m: k=16m+lh*4+r, c=c0+16w+l15
  bf16x8 na; float4 v0, v1;

  auto LOAD = [&](int s) {
    na = *reinterpret_cast<const bf16x8*>(at + abase + s * 32);
    size_t o0 = xbase0 + s * 32; if (o0 > TOT_X - 4) o0 = TOT_X - 4;
    size_t o1 = xbase1 + s * 32; if (o1 > TOT_X - 4) o1 = TOT_X - 4;
    v0 = *reinterpret_cast<const float4*>(x + o0);
    v1 = *reinterpret_cast<const float4*>(x + o1);
  };
  auto STORE = [&](int b) {
    *reinterpret_cast<bf16x8*>(&Al[b][ak][ach * 8]) = na;
    bf16x4 p0 = { (__bf16)v0.x, (__bf16)v0.y, (__bf16)v0.z, (__bf16)v0.w };
    bf16x4 p1 = { (__bf16)v1.x, (__bf16)v1.y, (__bf16)v1.z, (__bf16)v1.w };
    *reinterpret_cast<bf16x4*>(&Xl[b][xc][xch * 4])      = p0;
    *reinterpret_cast<bf16x4*>(&Xl[b][xc + 32][xch * 4]) = p1;
  };

  LOAD(0); STORE(0);
  __syncthreads();

  #pragma unroll 2
  for (int s = 0; s < 29; ++s) {     // K-dim p: 29 steps of 32 (at pad = 0)
    if (s < 28) LOAD(s + 1);
    bf16x8 b = *reinterpret_cast<const bf16x8*>(&Xl[s & 1][16 * w + l15][lh * 8]);
    #pragma unroll
    for (int m = 0; m < 4; ++m) {
      bf16x8 a = *reinterpret_cast<const bf16x8*>(&Al[s & 1][16 * m + l15][lh * 8]);
      acc[m] = __builtin_amdgcn_mfma_f32_16x16x32_bf16(a, b, acc[m], 0, 0, 0);
    }
    if (s < 28) STORE((s + 1) & 1);
    __syncthreads();
  }

  const int c = c0 + 16 * w + l15;
  #pragma unroll
  for (int m = 0; m < 4; ++m) {
    #pragma unroll
    for (int r = 0; r < 4; ++r) {
      const int k = 16 * m + lh * 4 + r;
      out[((size_t)n * K_ + k) * C_ + c] =
          acc[m][r] - asum[n * K_ + k] * cent[(size_t)k * C_ + c];
    }
  }
}

extern "C" void kernel_launch(void* const* d_in, const int* in_sizes, int n_in,
                              void* d_out, int out_size, void* d_ws, size_t ws_size,
                              hipStream_t stream) {
  const float* x    = (const float*)d_in[0];
  const float* w    = (const float*)d_in[1];
  const float* cent = (const float*)d_in[2];
  float* out = (float*)d_out;
  char* wsb  = (char*)d_ws;
  __bf16* at   = (__bf16*)wsb;
  float*  asum = (float*)(wsb + ASUM_OFF);
  __bf16* wb   = (__bf16*)(wsb + WB_OFF);

  k_prep_w<<<dim3(32), dim3(256), 0, stream>>>(w, wb, asum);
  k_phase1<<<dim3(15, 64), dim3(256), 0, stream>>>(x, wb, at, asum);
  k_phase2<<<dim3(8, 64), dim3(256), 0, stream>>>(x, at, asum, cent, out);
}

// Round 6
// 70.545 us; speedup vs baseline: 1.2855x; 1.2855x over previous
//
#include <hip/hip_runtime.h>

typedef __attribute__((ext_vector_type(8))) __bf16 bf16x8;
typedef __attribute__((ext_vector_type(4))) __bf16 bf16x4;
typedef __attribute__((ext_vector_type(4))) float f32x4;

// barrier WITHOUT vmcnt drain: LDS ops must land, global loads stay in flight
#define LGKM_BAR() do { asm volatile("s_waitcnt lgkmcnt(0)" ::: "memory"); \
                        __builtin_amdgcn_s_barrier(); } while (0)

namespace {
constexpr int N_ = 64, C_ = 512, P_ = 900, K_ = 64;
constexpr int PP = 960;                               // padded P for at
constexpr size_t TOT_X = (size_t)N_ * C_ * P_;        // 117,964,800 floats
constexpr size_t AT_BYTES  = (size_t)N_ * K_ * PP * 2;        // bf16 a' [n][k][960]
constexpr size_t ASUM_OFF  = AT_BYTES;                        // f32 [n][k]
constexpr size_t WB_OFF    = ASUM_OFF + (size_t)N_ * K_ * 4;  // bf16 w [k][c]
}

// --- w f32 [K][C] -> bf16 [K][C]; also zero asum
__global__ __launch_bounds__(256) void k_prep_w(const float* __restrict__ w,
                                                __bf16* __restrict__ wb,
                                                float* __restrict__ asum) {
  const int t = blockIdx.x * 256 + threadIdx.x;
  const int i = t * 4;
  if (i < K_ * C_) {
    float4 v = *reinterpret_cast<const float4*>(w + i);
    wb[i]   = (__bf16)v.x; wb[i+1] = (__bf16)v.y;
    wb[i+2] = (__bf16)v.z; wb[i+3] = (__bf16)v.w;
  }
  if (t < N_ * K_) asum[t] = 0.f;
}

// --- phase 1: logits^T[k][p] via MFMA, fused ssq + maxless softmax.
//     4-deep global prefetch ring; raw barriers (no vmcnt drain).
__global__ __launch_bounds__(256) void k_phase1(const float* __restrict__ x,
                                                const __bf16* __restrict__ wb,
                                                __bf16* __restrict__ at,
                                                float* __restrict__ asum) {
  __shared__ __bf16 Xl[2][64][40];   // [buf][p][c32+pad]
  __shared__ float SsqP[64][5];
  __shared__ float Sw[64][5];
  const int n   = blockIdx.y;
  const int p0  = blockIdx.x * 64;
  const int tid = threadIdx.x;
  const int w   = tid >> 6, l = tid & 63;
  const int l15 = l & 15,  lh = l >> 4;

  // preload A fragments (w rows) for all 16 K-steps
  bf16x8 afr[16];
  #pragma unroll
  for (int s = 0; s < 16; ++s)
    afr[s] = *reinterpret_cast<const bf16x8*>(
        wb + (size_t)(16 * w + l15) * C_ + s * 32 + lh * 8);

  const size_t xbase = (size_t)n * C_ * P_ + p0 + l;   // p = p0 + l
  float nx[4][8];                     // 4-deep prefetch ring (batch b -> nx[b&3])
  float sq = 0.f;
  f32x4 acc[4] = {};                  // frag t: p=p0+16t+l15, k=16w+lh*4+r

  // prologue: issue batches 0..3
  #pragma unroll
  for (int b = 0; b < 4; ++b)
    #pragma unroll
    for (int j = 0; j < 8; ++j) {
      size_t off = xbase + (size_t)(b * 32 + w * 8 + j) * P_;
      if (off > TOT_X - 1) off = TOT_X - 1;
      nx[b][j] = x[off];
    }
  {                                   // convert+store batch 0
    bf16x8 pk;
    #pragma unroll
    for (int j = 0; j < 8; ++j) { sq = fmaf(nx[0][j], nx[0][j], sq); pk[j] = (__bf16)nx[0][j]; }
    *reinterpret_cast<bf16x8*>(&Xl[0][l][w * 8]) = pk;
  }
  LGKM_BAR();

  #pragma unroll
  for (int s = 0; s < 16; ++s) {
    if (s + 4 < 16) {                 // issue batch s+4 into slot s&3 (freed by store(s))
      #pragma unroll
      for (int j = 0; j < 8; ++j) {
        size_t off = xbase + (size_t)((s + 4) * 32 + w * 8 + j) * P_;
        if (off > TOT_X - 1) off = TOT_X - 1;
        nx[s & 3][j] = x[off];
      }
    }
    #pragma unroll
    for (int t = 0; t < 4; ++t) {
      bf16x8 b = *reinterpret_cast<const bf16x8*>(&Xl[s & 1][16 * t + l15][lh * 8]);
      acc[t] = __builtin_amdgcn_mfma_f32_16x16x32_bf16(afr[s], b, acc[t], 0, 0, 0);
    }
    if (s < 15) {                     // convert+store batch s+1 (issued 3 iters ago)
      bf16x8 pk;
      #pragma unroll
      for (int j = 0; j < 8; ++j) {
        const float v = nx[(s + 1) & 3][j];
        sq = fmaf(v, v, sq); pk[j] = (__bf16)v;
      }
      *reinterpret_cast<bf16x8*>(&Xl[(s + 1) & 1][l][w * 8]) = pk;
      LGKM_BAR();
    }
  }

  SsqP[l][w] = sq;                     // partial ssq for p=p0+l over this wave's c's
  __syncthreads();

  float invn[4], invs_[4];
  bool valid[4];
  #pragma unroll
  for (int t = 0; t < 4; ++t) {
    const int pl = 16 * t + l15;
    const float ss = SsqP[pl][0] + SsqP[pl][1] + SsqP[pl][2] + SsqP[pl][3];
    invn[t] = 1.f / fmaxf(sqrtf(ss), 1e-12f);
    valid[t] = (p0 + pl) < P_;
    float ps = 0.f;
    #pragma unroll
    for (int r = 0; r < 4; ++r) {
      acc[t][r] = __expf(acc[t][r] * invn[t]);   // maxless: |logit| <= ~0.5
      ps += acc[t][r];
    }
    ps += __shfl_xor(ps, 16, 64);
    ps += __shfl_xor(ps, 32, 64);
    if (lh == 0) Sw[pl][w] = ps;
  }
  __syncthreads();
  #pragma unroll
  for (int t = 0; t < 4; ++t) {
    const int pl = 16 * t + l15;
    invs_[t] = 1.f / (Sw[pl][0] + Sw[pl][1] + Sw[pl][2] + Sw[pl][3]);
  }

  // write a' (bf16) and asum atomics
  #pragma unroll
  for (int t = 0; t < 4; ++t) {
    const int p = p0 + 16 * t + l15;
    #pragma unroll
    for (int r = 0; r < 4; ++r) {
      const int k = 16 * w + lh * 4 + r;
      const float ar = acc[t][r] * invs_[t];
      at[((size_t)n * K_ + k) * PP + p] = valid[t] ? (__bf16)(ar * invn[t]) : (__bf16)0.f;
    }
  }
  #pragma unroll
  for (int r = 0; r < 4; ++r) {
    float v = 0.f;
    #pragma unroll
    for (int t = 0; t < 4; ++t)
      v += valid[t] ? acc[t][r] * invs_[t] : 0.f;
    v += __shfl_xor(v, 1, 64); v += __shfl_xor(v, 2, 64);
    v += __shfl_xor(v, 4, 64); v += __shfl_xor(v, 8, 64);
    if (l15 == 0)
      unsafeAtomicAdd(asum + n * K_ + 16 * w + lh * 4 + r, v);
  }
}

// --- phase 2: vlad[k][c] = sum_p a'[k][p] * x_bf16[c][p] - asum[k]*cent[k][c]
__global__ __launch_bounds__(256) void k_phase2(const float* __restrict__ x,
                                                const __bf16* __restrict__ at,
                                                const float* __restrict__ asum,
                                                const float* __restrict__ cent,
                                                float* __restrict__ out) {
  __shared__ __bf16 Al[2][64][40];   // [buf][k][p32+pad]
  __shared__ __bf16 Xl[2][64][40];   // [buf][c][p32+pad]
  const int n   = blockIdx.y;
  const int c0  = blockIdx.x * 64;
  const int tid = threadIdx.x;
  const int w   = tid >> 6, l = tid & 63;
  const int l15 = l & 15,  lh = l >> 4;

  const int ak  = tid >> 2, ach = tid & 3;      // A staging: k, p-octet
  const int xc  = tid >> 3, xch = tid & 7;      // X staging (×2): c, p-quad
  const size_t abase = ((size_t)n * K_ + ak) * PP + ach * 8;
  const size_t xbase0 = ((size_t)n * C_ + c0 + xc) * P_ + xch * 4;
  const size_t xbase1 = ((size_t)n * C_ + c0 + xc + 32) * P_ + xch * 4;

  f32x4 acc[4] = {};                 // frag m: k=16m+lh*4+r, c=c0+16w+l15
  bf16x8 na; float4 v0, v1;

  auto LOAD = [&](int s) {
    na = *reinterpret_cast<const bf16x8*>(at + abase + s * 32);
    size_t o0 = xbase0 + s * 32; if (o0 > TOT_X - 4) o0 = TOT_X - 4;
    size_t o1 = xbase1 + s * 32; if (o1 > TOT_X - 4) o1 = TOT_X - 4;
    v0 = *reinterpret_cast<const float4*>(x + o0);
    v1 = *reinterpret_cast<const float4*>(x + o1);
  };
  auto STORE = [&](int b) {
    *reinterpret_cast<bf16x8*>(&Al[b][ak][ach * 8]) = na;
    bf16x4 p0 = { (__bf16)v0.x, (__bf16)v0.y, (__bf16)v0.z, (__bf16)v0.w };
    bf16x4 p1 = { (__bf16)v1.x, (__bf16)v1.y, (__bf16)v1.z, (__bf16)v1.w };
    *reinterpret_cast<bf16x4*>(&Xl[b][xc][xch * 4])      = p0;
    *reinterpret_cast<bf16x4*>(&Xl[b][xc + 32][xch * 4]) = p1;
  };

  LOAD(0); STORE(0);
  LGKM_BAR();

  #pragma unroll 2
  for (int s = 0; s < 29; ++s) {     // K-dim p: 29 steps of 32 (at pad = 0)
    if (s < 28) LOAD(s + 1);
    bf16x8 b = *reinterpret_cast<const bf16x8*>(&Xl[s & 1][16 * w + l15][lh * 8]);
    #pragma unroll
    for (int m = 0; m < 4; ++m) {
      bf16x8 a = *reinterpret_cast<const bf16x8*>(&Al[s & 1][16 * m + l15][lh * 8]);
      acc[m] = __builtin_amdgcn_mfma_f32_16x16x32_bf16(a, b, acc[m], 0, 0, 0);
    }
    if (s < 28) STORE((s + 1) & 1);
    LGKM_BAR();
  }

  const int c = c0 + 16 * w + l15;
  #pragma unroll
  for (int m = 0; m < 4; ++m) {
    #pragma unroll
    for (int r = 0; r < 4; ++r) {
      const int k = 16 * m + lh * 4 + r;
      out[((size_t)n * K_ + k) * C_ + c] =
          acc[m][r] - asum[n * K_ + k] * cent[(size_t)k * C_ + c];
    }
  }
}

extern "C" void kernel_launch(void* const* d_in, const int* in_sizes, int n_in,
                              void* d_out, int out_size, void* d_ws, size_t ws_size,
                              hipStream_t stream) {
  const float* x    = (const float*)d_in[0];
  const float* w    = (const float*)d_in[1];
  const float* cent = (const float*)d_in[2];
  float* out = (float*)d_out;
  char* wsb  = (char*)d_ws;
  __bf16* at   = (__bf16*)wsb;
  float*  asum = (float*)(wsb + ASUM_OFF);
  __bf16* wb   = (__bf16*)(wsb + WB_OFF);

  k_prep_w<<<dim3(32), dim3(256), 0, stream>>>(w, wb, asum);
  k_phase1<<<dim3(15, 64), dim3(256), 0, stream>>>(x, wb, at, asum);
  k_phase2<<<dim3(8, 64), dim3(256), 0, stream>>>(x, at, asum, cent, out);
}